// Round 5
// baseline (91.992 us; speedup 1.0000x reference)
//
#include <hip/hip_runtime.h>
#include <math.h>

#define MM 2049
#define BB 16
#define NN 512
#define JH 1025            // half-spectrum (j = 0..1024)
#define JP 1040            // padded row stride for PSp (float2 units)
#define SZ 8               // s-pair-chunk split in k1
#define PCH 128            // pairs per chunk: 8*128 = 1024 pairs (s=1..1024)
#define JCH 5              // j-chunks of 256 (5*256 >= 1025)
#define Z2 8               // j-split in k2 (load balance: 640 blocks)
#define JB2 129            // 8*129 = 1032 >= 1025
#define TCH 5              // t-chunks of 256 (5*256 >= 1025; t in [0,1024])

static constexpr double D_TWO_PI    = 6.283185307179586476925286766559;
static constexpr double D_STEP      = D_TWO_PI / 2049.0;
static constexpr float  F_TWO_PI    = 6.28318530717958647692f;
static constexpr float  INV_4TAU    = 83333.33333333333f;   // 1/(4*3e-6)
static constexpr float  PI_OVER_TAU = 1047197.5511965977f;  // pi/tau
static constexpr float  TWO_TAU     = 6.0e-6f;              // 2*tau
static constexpr float  INV_2PI     = 0.15915494309189533f;
static constexpr float  INV_M       = 1.0f / 2049.0f;
static constexpr float  WINF        = 8.0f;

// ------------------------------------- spread + DFT1 (s-symmetry folded) ----
__global__ void k_sdft1(const float* __restrict__ x, float2* __restrict__ PSp) {
    __shared__ float  LA[PCH];
    __shared__ float  LB[PCH];
    __shared__ float2 SD[PCH];   // {sum, diff}
    __shared__ float  Lz;        // red[0] (z==0 only)
    const int b  = blockIdx.y;
    const int z  = blockIdx.z;
    const int a0 = 1 + PCH * z;            // A = [a0, a0+PCH-1]  subset of [1,1024]
    const int b0 = 2049 - PCH * (z + 1);   // B = [b0, b0+PCH-1]  mirror (2049-s)
    for (int i = threadIdx.x; i < PCH; i += 256) { LA[i] = 0.0f; LB[i] = 0.0f; }
    if (threadIdx.x == 0) Lz = 0.0f;
    __syncthreads();
    for (int n = threadIdx.x; n < NN; n += 256) {
        float xv = x[b * NN + n];
        float xa = xv * F_TWO_PI;
        float p  = xv * (float)MM;
        int m0 = (int)ceilf(p - WINF);  if (m0 < 0) m0 = 0;
        int m1 = (int)floorf(p + WINF); if (m1 > MM - 1) m1 = MM - 1;
        bool hitA = (m1 >= a0) && (m0 <= a0 + PCH - 1);
        bool hitB = (m1 >= b0) && (m0 <= b0 + PCH - 1);
        bool hit0 = (z == 0) && (m0 == 0);
        if (!(hitA || hitB || hit0)) continue;
        for (int m = m0; m <= m1; ++m) {
            float xg = (float)((double)m * D_STEP);
            float d  = xa - xg;
            float g  = expf(-(d * d) * INV_4TAU);
            unsigned ia = (unsigned)(m - a0);
            unsigned ib = (unsigned)(m - b0);
            if (ia < PCH) atomicAdd(&LA[ia], g);
            if (ib < PCH) atomicAdd(&LB[ib], g);
            if (hit0 && m == 0) atomicAdd(&Lz, g);
        }
    }
    __syncthreads();
    for (int i = threadIdx.x; i < PCH; i += 256) {
        float ra = LA[i], rb = LB[PCH - 1 - i];
        SD[i] = make_float2(ra + rb, ra - rb);
    }
    __syncthreads();
    const int j = blockIdx.x * 256 + threadIdx.x;
    if (j >= JH) return;
    float ct, st;   // rotation step e^{i*2pi*j/M}
    { float ang = (float)((double)j * D_STEP); __sincosf(ang, &st, &ct); }
    float c, s;     // phase at s = a0
    { int r0 = (j * a0) % MM; float ph = (float)((double)r0 * D_STEP); __sincosf(ph, &s, &c); }
    float accc = 0.0f, accs = 0.0f;
    #pragma unroll 4
    for (int i = 0; i < PCH; ++i) {
        float2 sd = SD[i];                  // LDS broadcast b64
        accc = fmaf(sd.x, c, accc);
        accs = fmaf(sd.y, s, accs);
        float t1 = s * st, t2 = s * ct;
        float cn = fmaf(c, ct, -t1);
        float sn = fmaf(c, st,  t2);
        c = cn; s = sn;
    }
    if (z == 0) accc += Lz;                 // s = 0 term (cos=1, sin=0)
    PSp[((size_t)b * SZ + z) * JP + j] = make_float2(accc, accs);
}

// ------------------------------ mid + DFT2 (t-symmetry), j-split partials ----
__global__ void k_dft2m(const float2* __restrict__ PSp,
                        const float* __restrict__ mRe0, const float* __restrict__ mIm0,
                        const float* __restrict__ mRe1, const float* __restrict__ mIm1,
                        float* __restrict__ irfp) {
    __shared__ float4 lab[JB2];
    const int b   = blockIdx.y;
    const int zj  = blockIdx.z;
    const int jb0 = zj * JB2;
    const int jb1 = min(jb0 + JB2, JH);
    const int cntj = jb1 - jb0;
    for (int i = threadIdx.x; i < cntj; i += 256) {
        const int j = jb0 + i;
        float cs = 0.0f, sn = 0.0f;
        const float2* base = PSp + (size_t)b * SZ * JP + j;
        #pragma unroll
        for (int z = 0; z < SZ; ++z) {
            float2 ps = base[(size_t)z * JP];
            cs += ps.x; sn += ps.y;
        }
        const int msh = j + 1024;
        const float jf = (float)j;
        const float d2 = PI_OVER_TAU * expf(jf * jf * TWO_TAU);
        const float fac = (j == 0) ? 1.0f : 2.0f;
        const float sc = INV_2PI * d2 * fac;
        float4 v;
        v.x =  sc * mRe1[msh] * cs;   // A  ch0 (channel swap from ifftshift)
        v.y =  sc * mRe0[msh] * cs;   // A  ch1
        v.z = -sc * mIm1[msh] * sn;   // Bd ch0
        v.w = -sc * mIm0[msh] * sn;   // Bd ch1
        lab[i] = v;
    }
    __syncthreads();
    const int t = blockIdx.x * 256 + threadIdx.x;
    if (t >= JH) return;
    float ct, st;   // rotation step e^{i*2pi*t/M}
    { float ang = (float)((double)t * D_STEP); __sincosf(ang, &st, &ct); }
    float c, s;     // phase at j = jb0
    { int r0 = (t * jb0) % MM; float ph = (float)((double)r0 * D_STEP); __sincosf(ph, &s, &c); }
    float E0 = 0.0f, O0 = 0.0f, E1 = 0.0f, O1 = 0.0f;
    #pragma unroll 4
    for (int i = 0; i < cntj; ++i) {
        float4 v = lab[i];                  // LDS broadcast b128
        E0 = fmaf(v.x, c, E0);
        O0 = fmaf(v.z, s, O0);
        E1 = fmaf(v.y, c, E1);
        O1 = fmaf(v.w, s, O1);
        float t1 = s * st, t2 = s * ct;
        float cn = fmaf(c, ct, -t1);
        float sn2 = fmaf(c, st,  t2);
        c = cn; s = sn2;
    }
    float* o = irfp + ((size_t)(zj * BB + b) * MM) * 2;
    o[t * 2 + 0] = (E0 - O0) * INV_M;
    o[t * 2 + 1] = (E1 - O1) * INV_M;
    if (t >= 1) {
        o[(MM - t) * 2 + 0] = (E0 + O0) * INV_M;
        o[(MM - t) * 2 + 1] = (E1 + O1) * INV_M;
    }
}

// ---------------------------------------------------------------- gather ----
// 64-thread blocks: 128 blocks -> 128 CUs active (was 32).
__global__ void k_gather(const float* __restrict__ x, const float* __restrict__ irfp,
                         float* __restrict__ out) {
    const int idx = blockIdx.x * 64 + threadIdx.x;  // b*NN + n
    if (idx >= BB * NN) return;
    const int b = idx / NN;
    float xv = x[idx];
    float xa = xv * F_TWO_PI;
    float p  = xv * (float)MM;
    int m0 = (int)ceilf(p - WINF);  if (m0 < 0) m0 = 0;
    int m1 = (int)floorf(p + WINF); if (m1 > MM - 1) m1 = MM - 1;
    float acc0 = 0.0f, acc1 = 0.0f;
    for (int m = m0; m <= m1; ++m) {
        float xg = (float)((double)m * D_STEP);
        float d  = xa - xg;
        float g  = expf(-(d * d) * INV_4TAU);
        float p0 = 0.0f, p1 = 0.0f;
        #pragma unroll
        for (int z = 0; z < Z2; ++z) {
            const float2* base = (const float2*)(irfp + ((size_t)(z * BB + b) * MM) * 2);
            float2 v = base[m];
            p0 += v.x;
            p1 += v.y;
        }
        acc0 = fmaf(g, p0, acc0);
        acc1 = fmaf(g, p1, acc1);
    }
    out[idx * 2 + 0] = acc0 * INV_M;
    out[idx * 2 + 1] = acc1 * INV_M;
}

// ---------------------------------------------------------------- launch ----
extern "C" void kernel_launch(void* const* d_in, const int* in_sizes, int n_in,
                              void* d_out, int out_size, void* d_ws, size_t ws_size,
                              hipStream_t stream) {
    const float* x    = (const float*)d_in[0];
    const float* mRe0 = (const float*)d_in[1];
    const float* mIm0 = (const float*)d_in[2];
    const float* mRe1 = (const float*)d_in[3];
    const float* mIm1 = (const float*)d_in[4];
    float* out = (float*)d_out;

    float2* PSp  = (float2*)d_ws;                              // [BB][SZ][JP] float2
    float*  irfp = (float*)d_ws + (size_t)2 * BB * SZ * JP;    // [Z2][BB][MM][2]

    k_sdft1 <<<dim3(JCH, BB, SZ), 256, 0, stream>>>(x, PSp);
    k_dft2m <<<dim3(TCH, BB, Z2), 256, 0, stream>>>(PSp, mRe0, mIm0, mRe1, mIm1, irfp);
    k_gather<<<(BB * NN + 63) / 64, 64, 0, stream>>>(x, irfp, out);
}

// Round 6
// 89.407 us; speedup vs baseline: 1.0289x; 1.0289x over previous
//
#include <hip/hip_runtime.h>
#include <math.h>

#define MM 2049
#define BB 16
#define NN 512
#define JH 1025            // half-spectrum (j = 0..1024)
#define JP 1040            // padded row stride for PSp (float2 units)
#define SZ 8               // s-pair-chunk split in k1
#define PCH 128            // pairs per chunk: 8*128 = 1024 pairs (s=1..1024)
#define JCH 5              // j-chunks of 256 (5*256 >= 1025)
#define Z2 4               // j-split in k2 (round-4 best: 320 blocks)
#define JB2 257            // 4*257 = 1028 >= 1025
#define TCH 5              // t-chunks of 256 (5*256 >= 1025; t in [0,1024])

static constexpr double D_TWO_PI    = 6.283185307179586476925286766559;
static constexpr double D_STEP      = D_TWO_PI / 2049.0;
static constexpr float  F_TWO_PI    = 6.28318530717958647692f;
static constexpr float  INV_4TAU    = 83333.33333333333f;   // 1/(4*3e-6)
static constexpr float  PI_OVER_TAU = 1047197.5511965977f;  // pi/tau
static constexpr float  TWO_TAU     = 6.0e-6f;              // 2*tau
static constexpr float  INV_2PI     = 0.15915494309189533f;
static constexpr float  INV_M       = 1.0f / 2049.0f;
static constexpr float  WINF        = 8.0f;

// ------------------------------------- spread + DFT1 (s-symmetry folded) ----
// Pairs (s, M-s), s in [1,1024]. Block (jchunk, b, z) spreads red over its
// pair ranges A=[a0, a0+127], B=[b0, b0+127] (B is the mirror of A), folds
// into sum/diff, then CS/SN partials for j = jchunk*256+tid via rotation.
__global__ void k_sdft1(const float* __restrict__ x, float2* __restrict__ PSp) {
    __shared__ float  LA[PCH];
    __shared__ float  LB[PCH];
    __shared__ float2 SD[PCH];   // {sum, diff}
    __shared__ float  Lz;        // red[0] (z==0 only)
    const int b  = blockIdx.y;
    const int z  = blockIdx.z;
    const int a0 = 1 + PCH * z;            // A = [a0, a0+PCH-1]  subset of [1,1024]
    const int b0 = 2049 - PCH * (z + 1);   // B = [b0, b0+PCH-1]  mirror (2049-s)
    for (int i = threadIdx.x; i < PCH; i += 256) { LA[i] = 0.0f; LB[i] = 0.0f; }
    if (threadIdx.x == 0) Lz = 0.0f;
    __syncthreads();
    for (int n = threadIdx.x; n < NN; n += 256) {
        float xv = x[b * NN + n];
        float xa = xv * F_TWO_PI;
        float p  = xv * (float)MM;
        int m0 = (int)ceilf(p - WINF);  if (m0 < 0) m0 = 0;
        int m1 = (int)floorf(p + WINF); if (m1 > MM - 1) m1 = MM - 1;
        bool hitA = (m1 >= a0) && (m0 <= a0 + PCH - 1);
        bool hitB = (m1 >= b0) && (m0 <= b0 + PCH - 1);
        bool hit0 = (z == 0) && (m0 == 0);
        if (!(hitA || hitB || hit0)) continue;
        for (int m = m0; m <= m1; ++m) {
            float xg = (float)((double)m * D_STEP);
            float d  = xa - xg;
            float g  = expf(-(d * d) * INV_4TAU);
            unsigned ia = (unsigned)(m - a0);
            unsigned ib = (unsigned)(m - b0);
            if (ia < PCH) atomicAdd(&LA[ia], g);
            if (ib < PCH) atomicAdd(&LB[ib], g);
            if (hit0 && m == 0) atomicAdd(&Lz, g);
        }
    }
    __syncthreads();
    // fold: pair of s=a0+i is s'=2049-a0-i = b0 + (PCH-1-i)
    for (int i = threadIdx.x; i < PCH; i += 256) {
        float ra = LA[i], rb = LB[PCH - 1 - i];
        SD[i] = make_float2(ra + rb, ra - rb);
    }
    __syncthreads();
    const int j = blockIdx.x * 256 + threadIdx.x;
    if (j >= JH) return;
    float ct, st;   // rotation step e^{i*2pi*j/M}
    { float ang = (float)((double)j * D_STEP); __sincosf(ang, &st, &ct); }
    float c, s;     // phase at s = a0
    { int r0 = (j * a0) % MM; float ph = (float)((double)r0 * D_STEP); __sincosf(ph, &s, &c); }
    float accc = 0.0f, accs = 0.0f;
    #pragma unroll 4
    for (int i = 0; i < PCH; ++i) {
        float2 sd = SD[i];                  // LDS broadcast b64
        accc = fmaf(sd.x, c, accc);
        accs = fmaf(sd.y, s, accs);
        float t1 = s * st, t2 = s * ct;
        float cn = fmaf(c, ct, -t1);
        float sn = fmaf(c, st,  t2);
        c = cn; s = sn;
    }
    if (z == 0) accc += Lz;                 // s = 0 term (cos=1, sin=0)
    PSp[((size_t)b * SZ + z) * JP + j] = make_float2(accc, accs);
}

// ------------------------------ mid + DFT2 (t-symmetry), j-split partials ----
// Block (tchunk, b, zj): stage weighted AB[j] for its j range (fold the 8
// s-partials, apply deconv^2 * mult channel-swapped), then for t in [0,1024]:
//   E_c = sum A_c cos(2pi jt/M),  O_c = sum Bd_c sin(2pi jt/M)
//   irf_part[t] = (E-O)/M,  irf_part[M-t] = (E+O)/M   (t>=1)
__global__ void k_dft2m(const float2* __restrict__ PSp,
                        const float* __restrict__ mRe0, const float* __restrict__ mIm0,
                        const float* __restrict__ mRe1, const float* __restrict__ mIm1,
                        float* __restrict__ irfp) {
    __shared__ float4 lab[JB2];
    const int b   = blockIdx.y;
    const int zj  = blockIdx.z;
    const int jb0 = zj * JB2;
    const int jb1 = min(jb0 + JB2, JH);
    const int cntj = jb1 - jb0;
    for (int i = threadIdx.x; i < cntj; i += 256) {
        const int j = jb0 + i;
        float cs = 0.0f, sn = 0.0f;
        const float2* base = PSp + (size_t)b * SZ * JP + j;
        #pragma unroll
        for (int z = 0; z < SZ; ++z) {
            float2 ps = base[(size_t)z * JP];
            cs += ps.x; sn += ps.y;
        }
        const int msh = j + 1024;
        const float jf = (float)j;
        const float d2 = PI_OVER_TAU * expf(jf * jf * TWO_TAU);
        const float fac = (j == 0) ? 1.0f : 2.0f;
        const float sc = INV_2PI * d2 * fac;
        float4 v;
        v.x =  sc * mRe1[msh] * cs;   // A  ch0 (channel swap from ifftshift)
        v.y =  sc * mRe0[msh] * cs;   // A  ch1
        v.z = -sc * mIm1[msh] * sn;   // Bd ch0
        v.w = -sc * mIm0[msh] * sn;   // Bd ch1
        lab[i] = v;
    }
    __syncthreads();
    const int t = blockIdx.x * 256 + threadIdx.x;
    if (t >= JH) return;
    float ct, st;   // rotation step e^{i*2pi*t/M}
    { float ang = (float)((double)t * D_STEP); __sincosf(ang, &st, &ct); }
    float c, s;     // phase at j = jb0
    { int r0 = (t * jb0) % MM; float ph = (float)((double)r0 * D_STEP); __sincosf(ph, &s, &c); }
    float E0 = 0.0f, O0 = 0.0f, E1 = 0.0f, O1 = 0.0f;
    #pragma unroll 4
    for (int i = 0; i < cntj; ++i) {
        float4 v = lab[i];                  // LDS broadcast b128
        E0 = fmaf(v.x, c, E0);
        O0 = fmaf(v.z, s, O0);
        E1 = fmaf(v.y, c, E1);
        O1 = fmaf(v.w, s, O1);
        float t1 = s * st, t2 = s * ct;
        float cn = fmaf(c, ct, -t1);
        float sn2 = fmaf(c, st,  t2);
        c = cn; s = sn2;
    }
    float* o = irfp + ((size_t)(zj * BB + b) * MM) * 2;
    o[t * 2 + 0] = (E0 - O0) * INV_M;
    o[t * 2 + 1] = (E1 - O1) * INV_M;
    if (t >= 1) {
        o[(MM - t) * 2 + 0] = (E0 + O0) * INV_M;
        o[(MM - t) * 2 + 1] = (E1 + O1) * INV_M;
    }
}

// ---------------------------------------------------------------- gather ----
// fmm[b,n,c] = (1/M) sum_m g[b,n,m] * (sum_zj irfp[zj,b,m,c])  (windowed)
__global__ void k_gather(const float* __restrict__ x, const float* __restrict__ irfp,
                         float* __restrict__ out) {
    const int idx = blockIdx.x * blockDim.x + threadIdx.x;  // b*NN + n
    if (idx >= BB * NN) return;
    const int b = idx / NN;
    float xv = x[idx];
    float xa = xv * F_TWO_PI;
    float p  = xv * (float)MM;
    int m0 = (int)ceilf(p - WINF);  if (m0 < 0) m0 = 0;
    int m1 = (int)floorf(p + WINF); if (m1 > MM - 1) m1 = MM - 1;
    float acc0 = 0.0f, acc1 = 0.0f;
    for (int m = m0; m <= m1; ++m) {
        float xg = (float)((double)m * D_STEP);
        float d  = xa - xg;
        float g  = expf(-(d * d) * INV_4TAU);
        float p0 = 0.0f, p1 = 0.0f;
        #pragma unroll
        for (int z = 0; z < Z2; ++z) {
            const float2* base = (const float2*)(irfp + ((size_t)(z * BB + b) * MM) * 2);
            float2 v = base[m];
            p0 += v.x;
            p1 += v.y;
        }
        acc0 = fmaf(g, p0, acc0);
        acc1 = fmaf(g, p1, acc1);
    }
    out[idx * 2 + 0] = acc0 * INV_M;
    out[idx * 2 + 1] = acc1 * INV_M;
}

// ---------------------------------------------------------------- launch ----
extern "C" void kernel_launch(void* const* d_in, const int* in_sizes, int n_in,
                              void* d_out, int out_size, void* d_ws, size_t ws_size,
                              hipStream_t stream) {
    const float* x    = (const float*)d_in[0];
    const float* mRe0 = (const float*)d_in[1];
    const float* mIm0 = (const float*)d_in[2];
    const float* mRe1 = (const float*)d_in[3];
    const float* mIm1 = (const float*)d_in[4];
    float* out = (float*)d_out;

    float2* PSp  = (float2*)d_ws;                              // [BB][SZ][JP] float2
    float*  irfp = (float*)d_ws + (size_t)2 * BB * SZ * JP;    // [Z2][BB][MM][2]

    k_sdft1 <<<dim3(JCH, BB, SZ), 256, 0, stream>>>(x, PSp);
    k_dft2m <<<dim3(TCH, BB, Z2), 256, 0, stream>>>(PSp, mRe0, mIm0, mRe1, mIm1, irfp);
    k_gather<<<(BB * NN + 255) / 256, 256, 0, stream>>>(x, irfp, out);
}